// Round 3
// baseline (780.973 us; speedup 1.0000x reference)
//
#include <hip/hip_runtime.h>
#include <math.h>

#define Nn 80000
#define Dd 1000
#define KP 1024
#define Ee 1280000
#define MM 64000
#define SB 1024
#define NB 79   // ceil(Nn/SB)

typedef __attribute__((ext_vector_type(8))) short bf16x8;
typedef __attribute__((ext_vector_type(4))) short bf16x4;
typedef __attribute__((ext_vector_type(4))) float f32x4;
typedef __attribute__((ext_vector_type(4))) int i32x4;

__device__ inline unsigned short f2bf(float f){
  union { float f; unsigned u; } c; c.f = f;
  unsigned u = c.u;
  u += 0x7FFFu + ((u >> 16) & 1u);
  return (unsigned short)(u >> 16);
}

// ---- init: Wc=[W1|WdecT] bf16 [96][1024]; WdT2 [1008][32] bf16; tw[97];
//      zero flags/deg ------------------------------------------------------
__global__ __launch_bounds__(256) void k_init(const float* __restrict__ W1,
    const float* __restrict__ Wdec, const float* __restrict__ token,
    unsigned short* __restrict__ Wc, unsigned short* __restrict__ WdT2,
    float* __restrict__ tw, int* __restrict__ flags, int* __restrict__ deg)
{
  int i = blockIdx.x*256 + threadIdx.x;   // grid 512 blocks -> 131072 threads
  if (i < 96*1024){
    int n = i >> 10, k = i & 1023;
    float v = 0.f;
    if (k < Dd) v = (n < 64) ? W1[k*64 + n] : Wdec[(size_t)(n-64)*Dd + k];
    Wc[i] = f2bf(v);
  }
  unsigned t1 = (unsigned)(i - 98304);
  if (t1 < 32256u){                       // WdT2[col][k] = Wdec[k][col]
    int col = t1 >> 5, k = t1 & 31;
    WdT2[t1] = (col < Dd) ? f2bf(Wdec[(size_t)k*Dd + col]) : (unsigned short)0;
  }
  unsigned t2 = (unsigned)(i - 40000);
  if (t2 < (unsigned)Nn){ flags[t2] = 0; deg[t2] = 0; }
  if (i >= 130560){
    int j = i - 130560;
    if (j < 96){
      float s = 0.f;
      if (j < 64){ for (int k = 0; k < Dd; ++k) s += token[k]*W1[k*64 + j]; }
      else { const float* wr = Wdec + (size_t)(j-64)*Dd;
             for (int k = 0; k < Dd; ++k) s += token[k]*wr[k]; }
      tw[j] = s;
    } else if (j == 96){
      float s = 0.f;
      for (int k = 0; k < Dd; ++k) s += token[k]*token[k];
      tw[96] = s;
    }
  }
}

// ---- scatter mask flags + degree histogram --------------------------------
__global__ __launch_bounds__(256) void k_scatter(const int* __restrict__ mask,
    const int* __restrict__ rows, int* __restrict__ flags, int* __restrict__ deg)
{
  int i = blockIdx.x*256 + threadIdx.x;
  if (i < MM) flags[mask[i]] = 1;
  if (i < Ee) atomicAdd(&deg[rows[i]], 1);
}

// ---- hierarchical scan -----------------------------------------------------
__global__ __launch_bounds__(256) void k_scan1(const int* __restrict__ deg,
    int* __restrict__ bsum)
{
  int base = blockIdx.x*SB + threadIdx.x*4;
  int s = 0;
  if (base + 3 < Nn){
    i32x4 v = *reinterpret_cast<const i32x4*>(&deg[base]);
    s = v.x + v.y + v.z + v.w;
  } else {
    for (int j = 0; j < 4; ++j) if (base + j < Nn) s += deg[base + j];
  }
  #pragma unroll
  for (int o = 32; o; o >>= 1) s += __shfl_down(s, o);
  __shared__ int red[4];
  if ((threadIdx.x & 63) == 0) red[threadIdx.x >> 6] = s;
  __syncthreads();
  if (threadIdx.x == 0) bsum[blockIdx.x] = red[0] + red[1] + red[2] + red[3];
}

__global__ __launch_bounds__(128) void k_scan2(int* __restrict__ bsum,
    int* __restrict__ rstart)
{
  __shared__ int sh[NB];
  int t = threadIdx.x;
  if (t < NB) sh[t] = bsum[t];
  __syncthreads();
  if (t == 0){
    int r = 0;
    for (int j = 0; j < NB; ++j){ int v = sh[j]; sh[j] = r; r += v; }
    rstart[Nn] = r;
  }
  __syncthreads();
  if (t < NB) bsum[t] = sh[t];
}

__global__ __launch_bounds__(256) void k_scan3(const int* __restrict__ deg,
    const int* __restrict__ bsum, int* __restrict__ rstart, int* __restrict__ cursor)
{
  __shared__ int tsum[256];
  __shared__ int pref[256];
  int t = threadIdx.x;
  int base = blockIdx.x*SB + t*4;
  int d0=0,d1=0,d2=0,d3=0;
  if (base + 3 < Nn){
    i32x4 v = *reinterpret_cast<const i32x4*>(&deg[base]);
    d0=v.x; d1=v.y; d2=v.z; d3=v.w;
  } else {
    if (base   < Nn) d0 = deg[base];
    if (base+1 < Nn) d1 = deg[base+1];
    if (base+2 < Nn) d2 = deg[base+2];
    if (base+3 < Nn) d3 = deg[base+3];
  }
  tsum[t] = d0+d1+d2+d3;
  __syncthreads();
  if (t == 0){
    int r = 0;
    for (int j = 0; j < 256; ++j){ pref[j] = r; r += tsum[j]; }
  }
  __syncthreads();
  int off = pref[t] + bsum[blockIdx.x];
  int o0 = off, o1 = off+d0, o2 = off+d0+d1, o3 = off+d0+d1+d2;
  if (base + 3 < Nn){
    i32x4 w; w.x=o0; w.y=o1; w.z=o2; w.w=o3;
    *reinterpret_cast<i32x4*>(&rstart[base]) = w;
    *reinterpret_cast<i32x4*>(&cursor[base]) = w;
  } else {
    if (base   < Nn){ rstart[base]=o0;   cursor[base]=o0; }
    if (base+1 < Nn){ rstart[base+1]=o1; cursor[base+1]=o1; }
    if (base+2 < Nn){ rstart[base+2]=o2; cursor[base+2]=o2; }
    if (base+3 < Nn){ rstart[base+3]=o3; cursor[base+3]=o3; }
  }
}

// ---- CSR fill (paired col+val, one 8B store) -------------------------------
__global__ __launch_bounds__(256) void k_fill(const int* __restrict__ rows,
    const int* __restrict__ cols, const float* __restrict__ vals,
    int* __restrict__ cursor, int2* __restrict__ csre)
{
  int e = blockIdx.x*256 + threadIdx.x;
  if (e >= Ee) return;
  int r = rows[e];
  int p = atomicAdd(&cursor[r], 1);
  int2 pr; pr.x = cols[e]; pr.y = __float_as_int(vals[e]);
  csre[p] = pr;
}

// ---- GEMM1: [out_x]@[W1|WdecT] + BN/ELU + enc L2 + sii --------------------
__global__ __launch_bounds__(256) void k_gemm1(
    const float* __restrict__ x, const unsigned short* __restrict__ Wc,
    const int* __restrict__ flags, const float* __restrict__ tw,
    const float* __restrict__ token,
    const float* __restrict__ b1, const float* __restrict__ g1,
    const float* __restrict__ be1, const float* __restrict__ rm1,
    const float* __restrict__ rv1, const float* __restrict__ W2,
    const float* __restrict__ b2, const float* __restrict__ g2,
    const float* __restrict__ be2, const float* __restrict__ rm2,
    const float* __restrict__ rv2, float* __restrict__ fx,
    float* __restrict__ wx, float* __restrict__ sii_node)
{
  __shared__ char smem[37888];
  unsigned short* As = (unsigned short*)smem;            // 128*40*2 = 10240
  unsigned short* Bs = (unsigned short*)(smem + 10240);  // 96*40*2  = 7680
  float* Hs  = (float*)smem;                             // 128*66*4 = 33792
  float* W2s = (float*)(smem + 33792);                   // 4096

  const int tid  = threadIdx.x;
  const int lane = tid & 63;
  const int wave = tid >> 6;
  const int wm = wave >> 1, wn = wave & 1;
  const int row0 = blockIdx.x * 128;

  for (int t = tid; t < 1024; t += 256) W2s[t] = W2[t];

  const int kq    = (tid & 7) * 4;
  const int rbase = tid >> 3;
  const float* xp[4];
  #pragma unroll
  for (int it = 0; it < 4; ++it)
    xp[it] = x + (size_t)(row0 + it*32 + rbase) * Dd;

  const f32x4 zero4 = {0.f,0.f,0.f,0.f};
  f32x4 acc[4][3];
  #pragma unroll
  for (int i = 0; i < 4; ++i){ acc[i][0] = zero4; acc[i][1] = zero4; acc[i][2] = zero4; }
  float sx2[4] = {0.f,0.f,0.f,0.f};
  float sxt[4] = {0.f,0.f,0.f,0.f};

  for (int k0 = 0; k0 < KP; k0 += 32){
    int k = k0 + kq;
    bool kok = (k < Dd);
    f32x4 tok4 = zero4;
    if (kok) tok4 = *reinterpret_cast<const f32x4*>(token + k);
    #pragma unroll
    for (int it = 0; it < 4; ++it){
      bf16x4 pk;
      if (kok){
        f32x4 v = *reinterpret_cast<const f32x4*>(xp[it] + k);
        sx2[it] += v.x*v.x + v.y*v.y + v.z*v.z + v.w*v.w;
        sxt[it] += v.x*tok4.x + v.y*tok4.y + v.z*tok4.z + v.w*tok4.w;
        pk[0] = (short)f2bf(v.x); pk[1] = (short)f2bf(v.y);
        pk[2] = (short)f2bf(v.z); pk[3] = (short)f2bf(v.w);
      } else { pk[0]=0; pk[1]=0; pk[2]=0; pk[3]=0; }
      *reinterpret_cast<bf16x4*>(&As[(it*32 + rbase)*40 + kq]) = pk;
    }
    for (int c = tid; c < 384; c += 256){
      int brow = c >> 2, boff = (c & 3)*8;
      *reinterpret_cast<bf16x8*>(&Bs[brow*40 + boff]) =
          *reinterpret_cast<const bf16x8*>(&Wc[brow*KP + k0 + boff]);
    }
    __syncthreads();

    bf16x8 bfr[3];
    #pragma unroll
    for (int ni = 0; ni < 3; ++ni){
      int c = wn*48 + ni*16 + (lane & 15);
      bfr[ni] = *reinterpret_cast<const bf16x8*>(&Bs[c*40 + (lane>>4)*8]);
    }
    #pragma unroll
    for (int mi = 0; mi < 4; ++mi){
      int r = wm*64 + mi*16 + (lane & 15);
      bf16x8 af = *reinterpret_cast<const bf16x8*>(&As[r*40 + (lane>>4)*8]);
      acc[mi][0] = __builtin_amdgcn_mfma_f32_16x16x32_bf16(af, bfr[0], acc[mi][0], 0, 0, 0);
      acc[mi][1] = __builtin_amdgcn_mfma_f32_16x16x32_bf16(af, bfr[1], acc[mi][1], 0, 0, 0);
      acc[mi][2] = __builtin_amdgcn_mfma_f32_16x16x32_bf16(af, bfr[2], acc[mi][2], 0, 0, 0);
    }
    __syncthreads();
  }

  // sii_node: reduce over the 8 consecutive lanes sharing a row
  float stt = tw[96];
  #pragma unroll
  for (int it = 0; it < 4; ++it){
    float a2 = sx2[it], at = sxt[it];
    a2 += __shfl_xor(a2, 1); at += __shfl_xor(at, 1);
    a2 += __shfl_xor(a2, 2); at += __shfl_xor(at, 2);
    a2 += __shfl_xor(a2, 4); at += __shfl_xor(at, 4);
    if ((tid & 7) == 0){
      int row = row0 + it*32 + rbase;
      float fl = flags[row] ? 1.f : 0.f;
      sii_node[row] = a2 + fl*(2.f*at + stt);
    }
  }

  // per-output-row flags
  float flv[4][4];
  #pragma unroll
  for (int mi = 0; mi < 4; ++mi)
    #pragma unroll
    for (int r4 = 0; r4 < 4; ++r4)
      flv[mi][r4] = flags[row0 + wm*64 + mi*16 + (lane>>4)*4 + r4] ? 1.f : 0.f;

  // epilogue: cols <64 -> BN1+ELU into Hs; cols >=64 -> wx
  #pragma unroll
  for (int ni = 0; ni < 3; ++ni){
    int n = wn*48 + ni*16 + (lane & 15);
    float twn = tw[n];
    if (n < 64){
      float bb = b1[n], rmv = rm1[n];
      float scv = g1[n]*rsqrtf(rv1[n] + 1e-3f), bev = be1[n];
      #pragma unroll
      for (int mi = 0; mi < 4; ++mi){
        #pragma unroll
        for (int r4 = 0; r4 < 4; ++r4){
          int lrow = wm*64 + mi*16 + (lane>>4)*4 + r4;
          float v = (acc[mi][ni][r4] + flv[mi][r4]*twn + bb - rmv)*scv + bev;
          v = (v > 0.f) ? v : expm1f(v);
          Hs[lrow*66 + n] = v;
        }
      }
    } else {
      int j = n - 64;
      #pragma unroll
      for (int mi = 0; mi < 4; ++mi){
        #pragma unroll
        for (int r4 = 0; r4 < 4; ++r4){
          int lrow = wm*64 + mi*16 + (lane>>4)*4 + r4;
          wx[(size_t)(row0 + lrow)*32 + j] = acc[mi][ni][r4] + flv[mi][r4]*twn;
        }
      }
    }
  }
  __syncthreads();

  // phase 2: fx = elu(bn2(Hs @ W2 + b2))
  {
    int j = tid & 15;
    float pb = b2[j], prm = rm2[j];
    float psc = g2[j]*rsqrtf(rv2[j] + 1e-3f), pbe = be2[j];
    int rb = (tid >> 4) * 8;
    #pragma unroll
    for (int rr = 0; rr < 8; ++rr){
      int r = rb + rr;
      float a = pb;
      #pragma unroll
      for (int k = 0; k < 64; ++k) a += Hs[r*66 + k]*W2s[k*16 + j];
      float v = (a - prm)*psc + pbe;
      v = (v > 0.f) ? v : expm1f(v);
      fx[(size_t)(row0 + r)*16 + j] = v;
    }
  }
}

// ---- SpMM F=16 (afx from fx, amu from mu) ----------------------------------
__global__ __launch_bounds__(256) void k_spmm16(const int* __restrict__ rstart,
    const int2* __restrict__ csre, const float* __restrict__ in,
    float* __restrict__ out)
{
  int row = blockIdx.x*16 + (threadIdx.x >> 4);
  int l = threadIdx.x & 15;
  if (row >= Nn) return;
  int s = rstart[row], e = rstart[row+1];
  float acc = 0.f;
  for (int p = s; p < e; ++p){
    int2 ce = csre[p];
    acc += __int_as_float(ce.y) * in[(size_t)ce.x*16 + l];
  }
  out[(size_t)row*16 + l] = acc;
}

// ---- h1 = relu(afx @ Wgc1) ---------------------------------------------------
__global__ __launch_bounds__(256) void k_h1(const float* __restrict__ afx,
    const float* __restrict__ Wgc1, float* __restrict__ h1)
{
  __shared__ float Ws[16*64];
  for (int t = threadIdx.x; t < 1024; t += 256) Ws[t] = Wgc1[t];
  __syncthreads();
  int i = blockIdx.x*256 + threadIdx.x;
  if (i >= Nn*64) return;
  int row = i >> 6, j = i & 63;
  const float* ar = afx + (size_t)row*16;
  float acc = 0.f;
  #pragma unroll
  for (int k = 0; k < 16; ++k) acc += ar[k]*Ws[k*64 + j];
  h1[i] = fmaxf(acc, 0.f);
}

// ---- GCN2: ah = A@h1 (LDS) then mu/lv/z/gz ----------------------------------
__global__ __launch_bounds__(256) void k_gcn2(const int* __restrict__ rstart,
    const int2* __restrict__ csre, const float* __restrict__ h1,
    const float* __restrict__ Wgc2, const float* __restrict__ Wgc3,
    const float* __restrict__ fx, float* __restrict__ z, float* __restrict__ mu,
    float* __restrict__ lv, float* __restrict__ gz)
{
  __shared__ float ah[4][65];
  __shared__ float Ws[2048];
  int t = threadIdx.x;
  for (int i = t; i < 1024; i += 256){ Ws[i] = Wgc2[i]; Ws[1024 + i] = Wgc3[i]; }
  int row = blockIdx.x*4 + (t >> 6);
  int lane = t & 63;
  int s = rstart[row], e = rstart[row+1];
  float acc = 0.f;
  for (int p = s; p < e; ++p){
    int2 ce = csre[p];
    acc += __int_as_float(ce.y) * h1[(size_t)ce.x*64 + lane];
  }
  ah[t>>6][lane] = acc;
  __syncthreads();
  if (t < 128){
    int r = t >> 5, idx = t & 31, j = idx & 15, which = idx >> 4;
    const float* Wp = Ws + which*1024;
    const float* ar = ah[r];
    float sacc = 0.f;
    #pragma unroll 16
    for (int k = 0; k < 64; ++k) sacc += ar[k]*Wp[k*16 + j];
    size_t grow = (size_t)(blockIdx.x*4 + r);
    if (which == 0){
      mu[grow*16 + j] = sacc;
      gz[grow*16 + j] = sacc;
      z[grow*32 + 16 + j] = sacc;
    } else {
      lv[grow*16 + j] = sacc;
    }
  } else {
    int u = t - 128;
    int r = u >> 5, idx = u & 31;
    if (idx < 16){
      size_t grow = (size_t)(blockIdx.x*4 + r);
      z[grow*32 + idx] = fx[grow*16 + idx];
    }
  }
}

// ---- decoder: de = [afx|amu] @ Wdec via MFMA; srr fused ----------------------
__global__ __launch_bounds__(256) void k_dec(const float* __restrict__ afx,
    const float* __restrict__ amu, const unsigned short* __restrict__ WdT2,
    float* __restrict__ de, float* __restrict__ srr_node)
{
  const int lane = threadIdx.x & 63;
  const int wave = threadIdx.x >> 6;
  const int r0 = blockIdx.x*64 + wave*16;
  const int kg = lane >> 4;
  const int lr = lane & 15;
  const int arow = r0 + lr;
  const float* asrc = (kg < 2) ? (afx + (size_t)arow*16 + kg*8)
                               : (amu + (size_t)arow*16 + (kg-2)*8);
  f32x4 a0 = *reinterpret_cast<const f32x4*>(asrc);
  f32x4 a1 = *reinterpret_cast<const f32x4*>(asrc + 4);
  bf16x8 af;
  af[0]=(short)f2bf(a0.x); af[1]=(short)f2bf(a0.y);
  af[2]=(short)f2bf(a0.z); af[3]=(short)f2bf(a0.w);
  af[4]=(short)f2bf(a1.x); af[5]=(short)f2bf(a1.y);
  af[6]=(short)f2bf(a1.z); af[7]=(short)f2bf(a1.w);

  const f32x4 zero4 = {0.f,0.f,0.f,0.f};
  float sq0=0.f, sq1=0.f, sq2=0.f, sq3=0.f;
  const int drow = r0 + kg*4;
  for (int c0 = 0; c0 < 1008; c0 += 16){
    int col = c0 + lr;
    bf16x8 bf = *reinterpret_cast<const bf16x8*>(&WdT2[col*32 + kg*8]);
    f32x4 d = __builtin_amdgcn_mfma_f32_16x16x32_bf16(af, bf, zero4, 0, 0, 0);
    if (col < Dd){
      de[(size_t)(drow+0)*Dd + col] = d[0];
      de[(size_t)(drow+1)*Dd + col] = d[1];
      de[(size_t)(drow+2)*Dd + col] = d[2];
      de[(size_t)(drow+3)*Dd + col] = d[3];
      sq0 += d[0]*d[0]; sq1 += d[1]*d[1]; sq2 += d[2]*d[2]; sq3 += d[3]*d[3];
    }
  }
  #pragma unroll
  for (int o = 1; o < 16; o <<= 1){
    sq0 += __shfl_xor(sq0, o); sq1 += __shfl_xor(sq1, o);
    sq2 += __shfl_xor(sq2, o); sq3 += __shfl_xor(sq3, o);
  }
  if (lr == 0){
    srr_node[drow+0] = sq0; srr_node[drow+1] = sq1;
    srr_node[drow+2] = sq2; srr_node[drow+3] = sq3;
  }
}

// ---- q (student-t, alpha=1) --------------------------------------------------
__global__ __launch_bounds__(256) void k_q(const float* __restrict__ z,
    const float* __restrict__ cl, float* __restrict__ q)
{
  __shared__ float cls[320];
  int t = threadIdx.x;
  for (int i = t; i < 320; i += 256) cls[i] = cl[i];
  __syncthreads();
  int row = blockIdx.x*256 + t;
  if (row >= Nn) return;
  float zr[32];
  #pragma unroll
  for (int i = 0; i < 8; ++i){
    f32x4 v = *reinterpret_cast<const f32x4*>(&z[(size_t)row*32 + i*4]);
    zr[i*4] = v.x; zr[i*4+1] = v.y; zr[i*4+2] = v.z; zr[i*4+3] = v.w;
  }
  float qs[10], s = 0.f;
  #pragma unroll
  for (int c = 0; c < 10; ++c){
    float d2 = 0.f;
    #pragma unroll
    for (int k = 0; k < 32; ++k){ float d = zr[k] - cls[c*32 + k]; d2 += d*d; }
    float qq = 1.f/(1.f + d2);
    qs[c] = qq; s += qq;
  }
  float inv = 1.f/s;
  #pragma unroll
  for (int c = 0; c < 10; ++c) q[(size_t)row*10 + c] = qs[c]*inv;
}

// ---- loss: term per masked node + partial reduce -----------------------------
__global__ __launch_bounds__(256) void k_lossred(const float* __restrict__ afx,
    const float* __restrict__ amu, const float* __restrict__ wx,
    const float* __restrict__ sii_node, const float* __restrict__ srr_node,
    const int* __restrict__ mask, float* __restrict__ lpart)
{
  int i = blockIdx.x*256 + threadIdx.x;
  float s = 0.f;
  for (int w = i; w < MM; w += 64*256){
    int node = mask[w];
    const float* az1 = afx + (size_t)node*16;
    const float* az2 = amu + (size_t)node*16;
    const float* wv  = wx  + (size_t)node*32;
    float sri = 0.f;
    #pragma unroll
    for (int k = 0; k < 16; k += 4){
      f32x4 a = *reinterpret_cast<const f32x4*>(az1 + k);
      f32x4 b = *reinterpret_cast<const f32x4*>(wv + k);
      sri += a.x*b.x + a.y*b.y + a.z*b.z + a.w*b.w;
    }
    #pragma unroll
    for (int k = 0; k < 16; k += 4){
      f32x4 a = *reinterpret_cast<const f32x4*>(az2 + k);
      f32x4 b = *reinterpret_cast<const f32x4*>(wv + 16 + k);
      sri += a.x*b.x + a.y*b.y + a.z*b.z + a.w*b.w;
    }
    float nr = fmaxf(sqrtf(srr_node[node]), 1e-12f);
    float ni = fmaxf(sqrtf(sii_node[node]), 1e-12f);
    float tt = 1.f - sri/(nr*ni);
    s += tt*tt*tt;
  }
  #pragma unroll
  for (int o = 32; o; o >>= 1) s += __shfl_down(s, o);
  __shared__ float red[4];
  if ((threadIdx.x & 63) == 0) red[threadIdx.x >> 6] = s;
  __syncthreads();
  if (threadIdx.x == 0) lpart[blockIdx.x] = red[0] + red[1] + red[2] + red[3];
}

__global__ __launch_bounds__(64) void k_lsum(const float* __restrict__ lpart,
    float* __restrict__ loss)
{
  float v = lpart[threadIdx.x];
  #pragma unroll
  for (int o = 32; o; o >>= 1) v += __shfl_down(v, o);
  if (threadIdx.x == 0) *loss = v * (1.f/MM);
}

// ---- launch ------------------------------------------------------------------
extern "C" void kernel_launch(void* const* d_in, const int* in_sizes, int n_in,
                              void* d_out, int out_size, void* d_ws, size_t ws_size,
                              hipStream_t stream)
{
  const float* x     = (const float*)d_in[0];
  const int*   erow  = (const int*)  d_in[1];
  const int*   ecol  = (const int*)  d_in[2];
  const float* evls  = (const float*)d_in[3];
  const int*   mask  = (const int*)  d_in[4];
  const float* token = (const float*)d_in[5];
  const float* W1  = (const float*)d_in[6];
  const float* b1  = (const float*)d_in[7];
  const float* g1  = (const float*)d_in[8];
  const float* be1 = (const float*)d_in[9];
  const float* rm1 = (const float*)d_in[10];
  const float* rv1 = (const float*)d_in[11];
  const float* W2  = (const float*)d_in[12];
  const float* b2  = (const float*)d_in[13];
  const float* g2  = (const float*)d_in[14];
  const float* be2 = (const float*)d_in[15];
  const float* rm2 = (const float*)d_in[16];
  const float* rv2 = (const float*)d_in[17];
  const float* Wgc1= (const float*)d_in[18];
  const float* Wgc2= (const float*)d_in[19];
  const float* Wgc3= (const float*)d_in[20];
  const float* Wdec= (const float*)d_in[21];
  const float* clus= (const float*)d_in[22];

  float* out = (float*)d_out;
  float* oz  = out;
  float* omu = out + (size_t)Nn*32;
  float* olv = omu + (size_t)Nn*16;
  float* ode = olv + (size_t)Nn*16;
  float* oq  = ode + (size_t)Nn*1000;
  float* ofx = oq  + (size_t)Nn*10;
  float* ogz = ofx + (size_t)Nn*16;
  float* olo = ogz + (size_t)Nn*16;

  char* w = (char*)d_ws;
  unsigned short* Wc   = (unsigned short*)w; w += (size_t)96*KP*2;     // 196608
  unsigned short* WdT2 = (unsigned short*)w; w += (size_t)1008*32*2;   // 64512
  float* tw    = (float*)w; w += 512;
  int* flags   = (int*)w;   w += (size_t)Nn*4;
  int* deg     = (int*)w;   w += (size_t)Nn*4;
  int* rstart  = (int*)w;   w += (size_t)320512;
  int* cursor  = (int*)w;   w += (size_t)Nn*4;
  int* bsum    = (int*)w;   w += 512;
  int2* csre   = (int2*)w;  w += (size_t)Ee*8;
  float* afx   = (float*)w; w += (size_t)Nn*16*4;
  float* amu   = (float*)w; w += (size_t)Nn*16*4;
  float* h1    = (float*)w; w += (size_t)Nn*64*4;
  float* wx    = (float*)w; w += (size_t)Nn*32*4;
  float* sii   = (float*)w; w += (size_t)Nn*4;
  float* srr   = (float*)w; w += (size_t)Nn*4;
  float* lpart = (float*)w; w += 512;

  k_init<<<dim3(512), dim3(256), 0, stream>>>(W1, Wdec, token, Wc, WdT2, tw, flags, deg);
  k_scatter<<<dim3((Ee+255)/256), dim3(256), 0, stream>>>(mask, erow, flags, deg);
  k_scan1<<<dim3(NB), dim3(256), 0, stream>>>(deg, bsum);
  k_scan2<<<dim3(1), dim3(128), 0, stream>>>(bsum, rstart);
  k_scan3<<<dim3(NB), dim3(256), 0, stream>>>(deg, bsum, rstart, cursor);
  k_fill<<<dim3((Ee+255)/256), dim3(256), 0, stream>>>(erow, ecol, evls, cursor, csre);
  k_gemm1<<<dim3(Nn/128), dim3(256), 0, stream>>>(x, Wc, flags, tw, token,
      b1, g1, be1, rm1, rv1, W2, b2, g2, be2, rm2, rv2, ofx, wx, sii);
  k_spmm16<<<dim3(Nn/16), dim3(256), 0, stream>>>(rstart, csre, ofx, afx);
  k_h1<<<dim3((Nn*64+255)/256), dim3(256), 0, stream>>>(afx, Wgc1, h1);
  k_gcn2<<<dim3(Nn/4), dim3(256), 0, stream>>>(rstart, csre, h1, Wgc2, Wgc3,
      ofx, oz, omu, olv, ogz);
  k_spmm16<<<dim3(Nn/16), dim3(256), 0, stream>>>(rstart, csre, omu, amu);
  k_dec<<<dim3(Nn/64), dim3(256), 0, stream>>>(afx, amu, WdT2, ode, srr);
  k_q<<<dim3((Nn+255)/256), dim3(256), 0, stream>>>(oz, clus, oq);
  k_lossred<<<dim3(64), dim3(256), 0, stream>>>(afx, amu, wx, sii, srr, mask, lpart);
  k_lsum<<<dim3(1), dim3(64), 0, stream>>>(lpart, olo);
}

// Round 4
// 639.665 us; speedup vs baseline: 1.2209x; 1.2209x over previous
//
#include <hip/hip_runtime.h>
#include <hip/hip_bf16.h>
#include <math.h>

#define Nn 80000
#define Dd 1000
#define Ee 1280000
#define MM 64000
#define SB 1024
#define NB 79   // ceil(Nn/SB)
#define NT 32   // K tiles of 32

typedef __attribute__((ext_vector_type(8))) short bf16x8;
typedef __attribute__((ext_vector_type(4))) float f32x4;
typedef __attribute__((ext_vector_type(4))) int i32x4;

__device__ inline unsigned short f2bf(float f){
  union { float f; unsigned u; } c; c.f = f;
  unsigned u = c.u;
  u += 0x7FFFu + ((u >> 16) & 1u);
  return (unsigned short)(u >> 16);
}
__device__ inline float bf2f(unsigned short s){
  return __uint_as_float(((unsigned)s) << 16);
}

__device__ __forceinline__ void gload16(const void* g, void* l){
  __builtin_amdgcn_global_load_lds(
      (const __attribute__((address_space(1))) void*)g,
      (__attribute__((address_space(3))) void*)l, 16, 0, 0);
}

__device__ __forceinline__ bf16x8 cvt8(f32x4 a, f32x4 b){
  union { __hip_bfloat162 h; unsigned u; } c0, c1, c2, c3;
  c0.h = __float22bfloat162_rn(make_float2(a.x, a.y));
  c1.h = __float22bfloat162_rn(make_float2(a.z, a.w));
  c2.h = __float22bfloat162_rn(make_float2(b.x, b.y));
  c3.h = __float22bfloat162_rn(make_float2(b.z, b.w));
  union { unsigned u[4]; bf16x8 v; } r;
  r.u[0] = c0.u; r.u[1] = c1.u; r.u[2] = c2.u; r.u[3] = c3.u;
  return r.v;
}

// ---- init: Wim swizzled B image [32][96][8 x 16B]; WdT2; tw[97]; flags/deg --
__global__ __launch_bounds__(256) void k_init(const float* __restrict__ W1,
    const float* __restrict__ Wdec, const float* __restrict__ token,
    unsigned short* __restrict__ Wim, unsigned short* __restrict__ WdT2,
    float* __restrict__ tw, int* __restrict__ flags, int* __restrict__ deg)
{
  int i = blockIdx.x*256 + threadIdx.x;   // grid 919 blocks = 235264 threads
  if (i < 196608){
    int tt  = i / 6144;
    int rem = i - tt*6144;
    int c   = rem >> 6;
    int pos = rem & 63;
    int u   = pos >> 3;
    int j   = pos & 7;
    int c4  = u ^ (c & 7);
    float v = 0.f;
    if (c4 < 4){
      int k = tt*32 + c4*8 + j;
      if (k < Dd) v = (c < 64) ? W1[k*64 + c] : Wdec[(size_t)(c-64)*Dd + k];
    }
    Wim[i] = f2bf(v);
  }
  unsigned t1 = (unsigned)(i - 196608);
  if (t1 < 32256u){                       // WdT2[col][k] = Wdec[k][col]
    int col = t1 >> 5, k = t1 & 31;
    WdT2[t1] = (col < Dd) ? f2bf(Wdec[(size_t)k*Dd + col]) : (unsigned short)0;
  }
  if (i < Nn){ flags[i] = 0; deg[i] = 0; }
  unsigned u3 = (unsigned)(i - 228864);
  if (u3 < 6208u){                        // tw: one wave per output j
    int j = u3 >> 6, l = u3 & 63;
    float s = 0.f;
    if (j < 64){ for (int k = l; k < Dd; k += 64) s += token[k]*W1[k*64 + j]; }
    else if (j < 96){ const float* wr = Wdec + (size_t)(j-64)*Dd;
                      for (int k = l; k < Dd; k += 64) s += token[k]*wr[k]; }
    else { for (int k = l; k < Dd; k += 64) s += token[k]*token[k]; }
    #pragma unroll
    for (int o = 32; o; o >>= 1) s += __shfl_down(s, o);
    if (l == 0) tw[j] = s;
  }
}

// ---- scatter mask flags + degree histogram --------------------------------
__global__ __launch_bounds__(256) void k_scatter(const int* __restrict__ mask,
    const int* __restrict__ rows, int* __restrict__ flags, int* __restrict__ deg)
{
  int i = blockIdx.x*256 + threadIdx.x;
  if (i < MM) flags[mask[i]] = 1;
  if (i < Ee) atomicAdd(&deg[rows[i]], 1);
}

// ---- hierarchical scan -----------------------------------------------------
__global__ __launch_bounds__(256) void k_scan1(const int* __restrict__ deg,
    int* __restrict__ bsum)
{
  int base = blockIdx.x*SB + threadIdx.x*4;
  int s = 0;
  if (base + 3 < Nn){
    i32x4 v = *reinterpret_cast<const i32x4*>(&deg[base]);
    s = v.x + v.y + v.z + v.w;
  } else {
    for (int j = 0; j < 4; ++j) if (base + j < Nn) s += deg[base + j];
  }
  #pragma unroll
  for (int o = 32; o; o >>= 1) s += __shfl_down(s, o);
  __shared__ int red[4];
  if ((threadIdx.x & 63) == 0) red[threadIdx.x >> 6] = s;
  __syncthreads();
  if (threadIdx.x == 0) bsum[blockIdx.x] = red[0] + red[1] + red[2] + red[3];
}

__global__ __launch_bounds__(128) void k_scan2(int* __restrict__ bsum,
    int* __restrict__ rstart)
{
  __shared__ int sh[NB];
  int t = threadIdx.x;
  if (t < NB) sh[t] = bsum[t];
  __syncthreads();
  if (t == 0){
    int r = 0;
    for (int j = 0; j < NB; ++j){ int v = sh[j]; sh[j] = r; r += v; }
    rstart[Nn] = r;
  }
  __syncthreads();
  if (t < NB) bsum[t] = sh[t];
}

__global__ __launch_bounds__(256) void k_scan3(const int* __restrict__ deg,
    const int* __restrict__ bsum, int* __restrict__ rstart, int* __restrict__ cursor)
{
  __shared__ int tsum[256];
  __shared__ int pref[256];
  int t = threadIdx.x;
  int base = blockIdx.x*SB + t*4;
  int d0=0,d1=0,d2=0,d3=0;
  if (base + 3 < Nn){
    i32x4 v = *reinterpret_cast<const i32x4*>(&deg[base]);
    d0=v.x; d1=v.y; d2=v.z; d3=v.w;
  } else {
    if (base   < Nn) d0 = deg[base];
    if (base+1 < Nn) d1 = deg[base+1];
    if (base+2 < Nn) d2 = deg[base+2];
    if (base+3 < Nn) d3 = deg[base+3];
  }
  tsum[t] = d0+d1+d2+d3;
  __syncthreads();
  if (t == 0){
    int r = 0;
    for (int j = 0; j < 256; ++j){ pref[j] = r; r += tsum[j]; }
  }
  __syncthreads();
  int off = pref[t] + bsum[blockIdx.x];
  int o0 = off, o1 = off+d0, o2 = off+d0+d1, o3 = off+d0+d1+d2;
  if (base + 3 < Nn){
    i32x4 w; w.x=o0; w.y=o1; w.z=o2; w.w=o3;
    *reinterpret_cast<i32x4*>(&rstart[base]) = w;
    *reinterpret_cast<i32x4*>(&cursor[base]) = w;
  } else {
    if (base   < Nn){ rstart[base]=o0;   cursor[base]=o0; }
    if (base+1 < Nn){ rstart[base+1]=o1; cursor[base+1]=o1; }
    if (base+2 < Nn){ rstart[base+2]=o2; cursor[base+2]=o2; }
    if (base+3 < Nn){ rstart[base+3]=o3; cursor[base+3]=o3; }
  }
}

// ---- CSR fill (paired col+val) ----------------------------------------------
__global__ __launch_bounds__(256) void k_fill(const int* __restrict__ rows,
    const int* __restrict__ cols, const float* __restrict__ vals,
    int* __restrict__ cursor, int2* __restrict__ csre)
{
  int e = blockIdx.x*256 + threadIdx.x;
  if (e >= Ee) return;
  int r = rows[e];
  int p = atomicAdd(&cursor[r], 1);
  int2 pr; pr.x = cols[e]; pr.y = __float_as_int(vals[e]);
  csre[p] = pr;
}

// ---- GEMM1: async-pipelined [out_x]@[W1|WdecT] + BN/ELU + enc L2 + sii ------
// LDS map (bytes): A0 0..16384, A1 16384..32768, B0 32768..45056,
//                  B1 45056..57344, token 57344..61440.
// Phase2 reuse: Hs 0..33792, W2s 36864..40960.
__global__ __launch_bounds__(256, 2) void k_gemm1(
    const float* __restrict__ x, const unsigned short* __restrict__ Wim,
    const int* __restrict__ flags, const float* __restrict__ tw,
    const float* __restrict__ token,
    const float* __restrict__ b1, const float* __restrict__ g1,
    const float* __restrict__ be1, const float* __restrict__ rm1,
    const float* __restrict__ rv1, const float* __restrict__ W2,
    const float* __restrict__ b2, const float* __restrict__ g2,
    const float* __restrict__ be2, const float* __restrict__ rm2,
    const float* __restrict__ rv2, float* __restrict__ fx,
    float* __restrict__ wx, float* __restrict__ sii_node)
{
  __shared__ char smem[61440];
  float* tokL = (float*)(smem + 57344);
  const int tid  = threadIdx.x;
  const int lane = tid & 63;
  const int wave = tid >> 6;
  const int wm = wave >> 1, wn = wave & 1;
  const int l15 = lane & 15, kg = lane >> 4;
  const int swz = l15 & 7;
  const int row0 = blockIdx.x * 128;

  for (int i = tid; i < 1024; i += 256) tokL[i] = (i < Dd) ? token[i] : 0.f;
  __syncthreads();   // token visible before loop; before async stages

  auto stage = [&](int t, char* Ab, char* Bb){
    int k0 = t*32;
    #pragma unroll
    for (int j = 0; j < 4; ++j){           // A: 16KB, 4 x 1KB chunks/wave
      int s = (wave*4 + j)*64 + lane;
      int r = s >> 3, u = s & 7;
      int col = k0 + ((u ^ (r & 7)) << 2);
      if (col > 996) col = 996;
      gload16(x + (size_t)(row0 + r)*Dd + col, Ab + (wave*4 + j)*1024);
    }
    const char* wim = (const char*)Wim + (size_t)t*12288;
    #pragma unroll
    for (int j = 0; j < 3; ++j){           // B: 12KB, 3 x 1KB chunks/wave
      int ch = wave + j*4;
      gload16(wim + ch*1024 + lane*16, Bb + ch*1024);
    }
  };

  stage(0, smem,         smem + 32768);
  stage(1, smem + 16384, smem + 45056);

  const f32x4 zero4 = {0.f,0.f,0.f,0.f};
  f32x4 acc[4][3];
  #pragma unroll
  for (int i = 0; i < 4; ++i){ acc[i][0]=zero4; acc[i][1]=zero4; acc[i][2]=zero4; }
  float sx2[4] = {0.f,0.f,0.f,0.f};
  float sxt[4] = {0.f,0.f,0.f,0.f};

  #pragma unroll 2
  for (int t = 0; t < NT; ++t){
    if (t < NT-1) asm volatile("s_waitcnt vmcnt(7)" ::: "memory");
    else          asm volatile("s_waitcnt vmcnt(0)" ::: "memory");
    __builtin_amdgcn_s_barrier();
    __builtin_amdgcn_sched_barrier(0);

    const char* Ab = smem + (t&1)*16384;
    const char* Bb = smem + 32768 + (t&1)*12288;
    const int k0 = t*32;

    f32x4 tk0 = *(const f32x4*)(tokL + k0 + kg*8);
    f32x4 tk1 = *(const f32x4*)(tokL + k0 + kg*8 + 4);

    bf16x8 bfr[3];
    #pragma unroll
    for (int ni = 0; ni < 3; ++ni){
      int c = wn*48 + ni*16 + l15;
      bfr[ni] = *(const bf16x8*)(Bb + c*128 + ((kg ^ swz) << 4));
    }
    bool kv = (k0 + kg*8) <= 992;
    #pragma unroll
    for (int mi = 0; mi < 4; ++mi){
      int r = wm*64 + mi*16 + l15;
      f32x4 xa = *(const f32x4*)(Ab + r*128 + (((2*kg  ) ^ swz) << 4));
      f32x4 xb = *(const f32x4*)(Ab + r*128 + (((2*kg+1) ^ swz) << 4));
      if (wn == 0 && kv){
        sx2[mi] += xa.x*xa.x + xa.y*xa.y + xa.z*xa.z + xa.w*xa.w
                 + xb.x*xb.x + xb.y*xb.y + xb.z*xb.z + xb.w*xb.w;
        sxt[mi] += xa.x*tk0.x + xa.y*tk0.y + xa.z*tk0.z + xa.w*tk0.w
                 + xb.x*tk1.x + xb.y*tk1.y + xb.z*tk1.z + xb.w*tk1.w;
      }
      bf16x8 af = cvt8(xa, xb);
      acc[mi][0] = __builtin_amdgcn_mfma_f32_16x16x32_bf16(af, bfr[0], acc[mi][0], 0, 0, 0);
      acc[mi][1] = __builtin_amdgcn_mfma_f32_16x16x32_bf16(af, bfr[1], acc[mi][1], 0, 0, 0);
      acc[mi][2] = __builtin_amdgcn_mfma_f32_16x16x32_bf16(af, bfr[2], acc[mi][2], 0, 0, 0);
    }

    __builtin_amdgcn_sched_barrier(0);
    __builtin_amdgcn_s_barrier();
    if (t + 2 < NT)
      stage(t+2, smem + (t&1)*16384, smem + 32768 + (t&1)*12288);
  }

  // sii: reduce across kg groups (xor 16, 32); wn==0 waves own it
  float stt = tw[96];
  if (wn == 0){
    #pragma unroll
    for (int mi = 0; mi < 4; ++mi){
      float a2 = sx2[mi]; a2 += __shfl_xor(a2, 16); a2 += __shfl_xor(a2, 32);
      float at = sxt[mi]; at += __shfl_xor(at, 16); at += __shfl_xor(at, 32);
      if (lane < 16){
        int row = row0 + wm*64 + mi*16 + lane;
        float fl = flags[row] ? 1.f : 0.f;
        sii_node[row] = a2 + fl*(2.f*at + stt);
      }
    }
  }

  // per-output-row flags
  float flv[4][4];
  #pragma unroll
  for (int mi = 0; mi < 4; ++mi)
    #pragma unroll
    for (int r4 = 0; r4 < 4; ++r4)
      flv[mi][r4] = flags[row0 + wm*64 + mi*16 + (lane>>4)*4 + r4] ? 1.f : 0.f;

  float* Hs  = (float*)smem;
  float* W2s = (float*)(smem + 36864);
  for (int i = tid; i < 1024; i += 256) W2s[i] = W2[i];

  // epilogue: cols <64 -> BN1+ELU into Hs; cols >=64 -> wx
  #pragma unroll
  for (int ni = 0; ni < 3; ++ni){
    int n = wn*48 + ni*16 + l15;
    float twn = tw[n];
    if (n < 64){
      float bb = b1[n], rmv = rm1[n];
      float scv = g1[n]*rsqrtf(rv1[n] + 1e-3f), bev = be1[n];
      #pragma unroll
      for (int mi = 0; mi < 4; ++mi){
        #pragma unroll
        for (int r4 = 0; r4 < 4; ++r4){
          int lrow = wm*64 + mi*16 + (lane>>4)*4 + r4;
          float v = (acc[mi][ni][r4] + flv[mi][r4]*twn + bb - rmv)*scv + bev;
          v = (v > 0.f) ? v : expm1f(v);
          Hs[lrow*66 + n] = v;
        }
      }
    } else {
      int j = n - 64;
      #pragma unroll
      for (int mi = 0; mi < 4; ++mi){
        #pragma unroll
        for (int r4 = 0; r4 < 4; ++r4){
          int lrow = wm*64 + mi*16 + (lane>>4)*4 + r4;
          wx[(size_t)(row0 + lrow)*32 + j] = acc[mi][ni][r4] + flv[mi][r4]*twn;
        }
      }
    }
  }
  __syncthreads();

  // phase 2: fx = elu(bn2(Hs @ W2 + b2))
  {
    int j = tid & 15;
    float pb = b2[j], prm = rm2[j];
    float psc = g2[j]*rsqrtf(rv2[j] + 1e-3f), pbe = be2[j];
    int rb = (tid >> 4) * 8;
    #pragma unroll
    for (int rr = 0; rr < 8; ++rr){
      int r = rb + rr;
      float a = pb;
      #pragma unroll
      for (int k = 0; k < 64; ++k) a += Hs[r*66 + k]*W2s[k*16 + j];
      float v = (a - prm)*psc + pbe;
      v = (v > 0.f) ? v : expm1f(v);
      fx[(size_t)(row0 + r)*16 + j] = v;
    }
  }
}

// ---- SpMM F=16 (afx from fx, amu from mu) ----------------------------------
__global__ __launch_bounds__(256) void k_spmm16(const int* __restrict__ rstart,
    const int2* __restrict__ csre, const float* __restrict__ in,
    float* __restrict__ out)
{
  int row = blockIdx.x*16 + (threadIdx.x >> 4);
  int l = threadIdx.x & 15;
  if (row >= Nn) return;
  int s = rstart[row], e = rstart[row+1];
  float acc = 0.f;
  for (int p = s; p < e; ++p){
    int2 ce = csre[p];
    acc += __int_as_float(ce.y) * in[(size_t)ce.x*16 + l];
  }
  out[(size_t)row*16 + l] = acc;
}

// ---- h1 = relu(afx @ Wgc1) -> bf16 ------------------------------------------
__global__ __launch_bounds__(256) void k_h1(const float* __restrict__ afx,
    const float* __restrict__ Wgc1, unsigned short* __restrict__ h1b)
{
  __shared__ float Ws[16*64];
  for (int t = threadIdx.x; t < 1024; t += 256) Ws[t] = Wgc1[t];
  __syncthreads();
  int i = blockIdx.x*256 + threadIdx.x;
  if (i >= Nn*64) return;
  int row = i >> 6, j = i & 63;
  const float* ar = afx + (size_t)row*16;
  float acc = 0.f;
  #pragma unroll
  for (int k = 0; k < 16; ++k) acc += ar[k]*Ws[k*64 + j];
  h1b[i] = f2bf(fmaxf(acc, 0.f));
}

// ---- GCN2: ah = A@h1 (bf16 gather) then mu/lv/z/gz --------------------------
__global__ __launch_bounds__(256) void k_gcn2(const int* __restrict__ rstart,
    const int2* __restrict__ csre, const unsigned short* __restrict__ h1b,
    const float* __restrict__ Wgc2, const float* __restrict__ Wgc3,
    const float* __restrict__ fx, float* __restrict__ z, float* __restrict__ mu,
    float* __restrict__ lv, float* __restrict__ gz)
{
  __shared__ float ah[4][65];
  __shared__ float Ws[2048];
  int t = threadIdx.x;
  for (int i = t; i < 1024; i += 256){ Ws[i] = Wgc2[i]; Ws[1024 + i] = Wgc3[i]; }
  int row = blockIdx.x*4 + (t >> 6);
  int lane = t & 63;
  int s = rstart[row], e = rstart[row+1];
  float acc = 0.f;
  for (int p = s; p < e; ++p){
    int2 ce = csre[p];
    acc += __int_as_float(ce.y) * bf2f(h1b[(size_t)ce.x*64 + lane]);
  }
  ah[t>>6][lane] = acc;
  __syncthreads();
  if (t < 128){
    int r = t >> 5, idx = t & 31, j = idx & 15, which = idx >> 4;
    const float* Wp = Ws + which*1024;
    const float* ar = ah[r];
    float sacc = 0.f;
    #pragma unroll 16
    for (int k = 0; k < 64; ++k) sacc += ar[k]*Wp[k*16 + j];
    size_t grow = (size_t)(blockIdx.x*4 + r);
    if (which == 0){
      mu[grow*16 + j] = sacc;
      gz[grow*16 + j] = sacc;
      z[grow*32 + 16 + j] = sacc;
    } else {
      lv[grow*16 + j] = sacc;
    }
  } else {
    int u = t - 128;
    int r = u >> 5, idx = u & 31;
    if (idx < 16){
      size_t grow = (size_t)(blockIdx.x*4 + r);
      z[grow*32 + idx] = fx[grow*16 + idx];
    }
  }
}

// ---- decoder: de = [afx|amu] @ Wdec via MFMA; srr fused ----------------------
__global__ __launch_bounds__(256) void k_dec(const float* __restrict__ afx,
    const float* __restrict__ amu, const unsigned short* __restrict__ WdT2,
    float* __restrict__ de, float* __restrict__ srr_node)
{
  const int lane = threadIdx.x & 63;
  const int wave = threadIdx.x >> 6;
  const int r0 = blockIdx.x*64 + wave*16;
  const int kg = lane >> 4;
  const int lr = lane & 15;
  const int arow = r0 + lr;
  const float* asrc = (kg < 2) ? (afx + (size_t)arow*16 + kg*8)
                               : (amu + (size_t)arow*16 + (kg-2)*8);
  f32x4 a0 = *reinterpret_cast<const f32x4*>(asrc);
  f32x4 a1 = *reinterpret_cast<const f32x4*>(asrc + 4);
  bf16x8 af = cvt8(a0, a1);

  const f32x4 zero4 = {0.f,0.f,0.f,0.f};
  float sq0=0.f, sq1=0.f, sq2=0.f, sq3=0.f;
  const int drow = r0 + kg*4;
  for (int c0 = 0; c0 < 1008; c0 += 16){
    int col = c0 + lr;
    bf16x8 bf = *reinterpret_cast<const bf16x8*>(&WdT2[col*32 + kg*8]);
    f32x4 d = __builtin_amdgcn_mfma_f32_16x16x32_bf16(af, bf, zero4, 0, 0, 0);
    if (col < Dd){
      de[(size_t)(drow+0)*Dd + col] = d[0];
      de[(size_t)(drow+1)*Dd + col] = d[1];
      de[(size_t)(drow+2)*Dd + col] = d[2];
      de[(size_t)(drow+3)*Dd + col] = d[3];
      sq0 += d[0]*d[0]; sq1 += d[1]*d[1]; sq2 += d[2]*d[2]; sq3 += d[3]*d[3];
    }
  }
  #pragma unroll
  for (int o = 1; o < 16; o <<= 1){
    sq0 += __shfl_xor(sq0, o); sq1 += __shfl_xor(sq1, o);
    sq2 += __shfl_xor(sq2, o); sq3 += __shfl_xor(sq3, o);
  }
  if (lr == 0){
    srr_node[drow+0] = sq0; srr_node[drow+1] = sq1;
    srr_node[drow+2] = sq2; srr_node[drow+3] = sq3;
  }
}

// ---- q (student-t, alpha=1) --------------------------------------------------
__global__ __launch_bounds__(256) void k_q(const float* __restrict__ z,
    const float* __restrict__ cl, float* __restrict__ q)
{
  __shared__ float cls[320];
  int t = threadIdx.x;
  for (int i = t; i < 320; i += 256) cls[i] = cl[i];
  __syncthreads();
  int row = blockIdx.x*256 + t;
  if (row >= Nn) return;
  float zr[32];
  #pragma unroll
  for (int i = 0; i < 8; ++i){
    f32x4 v = *reinterpret_cast<const f32x4*>(&z[(size_t)row*32 + i*4]);
    zr[i*4] = v.x; zr[i*4+1] = v.y; zr[i*4+2] = v.z; zr[i*4+3] = v.w;
  }
  float qs[10], s = 0.f;
  #pragma unroll
  for (int c = 0; c < 10; ++c){
    float d2 = 0.f;
    #pragma unroll
    for (int k = 0; k < 32; ++k){ float d = zr[k] - cls[c*32 + k]; d2 += d*d; }
    float qq = 1.f/(1.f + d2);
    qs[c] = qq; s += qq;
  }
  float inv = 1.f/s;
  #pragma unroll
  for (int c = 0; c < 10; ++c) q[(size_t)row*10 + c] = qs[c]*inv;
}

// ---- loss: term per masked node + partial reduce -----------------------------
__global__ __launch_bounds__(256) void k_lossred(const float* __restrict__ afx,
    const float* __restrict__ amu, const float* __restrict__ wx,
    const float* __restrict__ sii_node, const float* __restrict__ srr_node,
    const int* __restrict__ mask, float* __restrict__ lpart)
{
  int i = blockIdx.x*256 + threadIdx.x;
  float s = 0.f;
  for (int w = i; w < MM; w += 64*256){
    int node = mask[w];
    const float* az1 = afx + (size_t)node*16;
    const float* az2 = amu + (size_t)node*16;
    const float* wv  = wx  + (size_t)node*32;
    float sri = 0.f;
    #pragma unroll
    for (int k = 0; k < 16; k += 4){
      f32x4 a = *reinterpret_cast<const f32x4*>(az1 + k);
      f32x4 b = *reinterpret_cast<const f32x4*>(wv + k);
      sri += a.x*b.x + a.y*b.y + a.z*b.z + a.w*b.w;
    }
    #pragma unroll
    for (int k = 0; k < 16; k += 4){
      f32x4 a = *reinterpret_cast<const f32x4*>(az2 + k);
      f32x4 b = *reinterpret_cast<const f32x4*>(wv + 16 + k);
      sri += a.x*b.x + a.y*b.y + a.z*b.z + a.w*b.w;
    }
    float nr = fmaxf(sqrtf(srr_node[node]), 1e-12f);
    float ni = fmaxf(sqrtf(sii_node[node]), 1e-12f);
    float tt = 1.f - sri/(nr*ni);
    s += tt*tt*tt;
  }
  #pragma unroll
  for (int o = 32; o; o >>= 1) s += __shfl_down(s, o);
  __shared__ float red[4];
  if ((threadIdx.x & 63) == 0) red[threadIdx.x >> 6] = s;
  __syncthreads();
  if (threadIdx.x == 0) lpart[blockIdx.x] = red[0] + red[1] + red[2] + red[3];
}

__global__ __launch_bounds__(64) void k_lsum(const float* __restrict__ lpart,
    float* __restrict__ loss)
{
  float v = lpart[threadIdx.x];
  #pragma unroll
  for (int o = 32; o; o >>= 1) v += __shfl_down(v, o);
  if (threadIdx.x == 0) *loss = v * (1.f/MM);
}

// ---- launch ------------------------------------------------------------------
extern "C" void kernel_launch(void* const* d_in, const int* in_sizes, int n_in,
                              void* d_out, int out_size, void* d_ws, size_t ws_size,
                              hipStream_t stream)
{
  const float* x     = (const float*)d_in[0];
  const int*   erow  = (const int*)  d_in[1];
  const int*   ecol  = (const int*)  d_in[2];
  const float* evls  = (const float*)d_in[3];
  const int*   mask  = (const int*)  d_in[4];
  const float* token = (const float*)d_in[5];
  const float* W1  = (const float*)d_in[6];
  const float* b1  = (const float*)d_in[7];
  const float* g1  = (const float*)d_in[8];
  const float* be1 = (const float*)d_in[9];
  const float* rm1 = (const float*)d_in[10];
  const float* rv1 = (const float*)d_in[11];
  const float* W2  = (const float*)d_in[12];
  const float* b2  = (const float*)d_in[13];
  const float* g2  = (const float*)d_in[14];
  const float* be2 = (const float*)d_in[15];
  const float* rm2 = (const float*)d_in[16];
  const float* rv2 = (const float*)d_in[17];
  const float* Wgc1= (const float*)d_in[18];
  const float* Wgc2= (const float*)d_in[19];
  const float* Wgc3= (const float*)d_in[20];
  const float* Wdec= (const float*)d_in[21];
  const float* clus= (const float*)d_in[22];

  float* out = (float*)d_out;
  float* oz  = out;
  float* omu = out + (size_t)Nn*32;
  float* olv = omu + (size_t)Nn*16;
  float* ode = olv + (size_t)Nn*16;
  float* oq  = ode + (size_t)Nn*1000;
  float* ofx = oq  + (size_t)Nn*10;
  float* ogz = ofx + (size_t)Nn*16;
  float* olo = ogz + (size_t)Nn*16;

  char* w = (char*)d_ws;
  unsigned short* Wim  = (unsigned short*)w; w += (size_t)393216;      // 32*96*64*2
  unsigned short* WdT2 = (unsigned short*)w; w += (size_t)64512;       // 1008*32*2
  float* tw    = (float*)w; w += 512;
  int* flags   = (int*)w;   w += (size_t)Nn*4;
  int* deg     = (int*)w;   w += (size_t)Nn*4;
  int* rstart  = (int*)w;   w += (size_t)320512;
  int* cursor  = (int*)w;   w += (size_t)Nn*4;
  int* bsum    = (int*)w;   w += 512;
  int2* csre   = (int2*)w;  w += (size_t)Ee*8;
  float* afx   = (float*)w; w += (size_t)Nn*16*4;
  float* amu   = (float*)w; w += (size_t)Nn*16*4;
  unsigned short* h1b = (unsigned short*)w; w += (size_t)Nn*64*2;
  float* wx    = (float*)w; w += (size_t)Nn*32*4;
  float* sii   = (float*)w; w += (size_t)Nn*4;
  float* srr   = (float*)w; w += (size_t)Nn*4;
  float* lpart = (float*)w; w += 512;

  k_init<<<dim3(919), dim3(256), 0, stream>>>(W1, Wdec, token, Wim, WdT2, tw, flags, deg);
  k_scatter<<<dim3((Ee+255)/256), dim3(256), 0, stream>>>(mask, erow, flags, deg);
  k_scan1<<<dim3(NB), dim3(256), 0, stream>>>(deg, bsum);
  k_scan2<<<dim3(1), dim3(128), 0, stream>>>(bsum, rstart);
  k_scan3<<<dim3(NB), dim3(256), 0, stream>>>(deg, bsum, rstart, cursor);
  k_fill<<<dim3((Ee+255)/256), dim3(256), 0, stream>>>(erow, ecol, evls, cursor, csre);
  k_gemm1<<<dim3(Nn/128), dim3(256), 0, stream>>>(x, Wim, flags, tw, token,
      b1, g1, be1, rm1, rv1, W2, b2, g2, be2, rm2, rv2, ofx, wx, sii);
  k_spmm16<<<dim3(Nn/16), dim3(256), 0, stream>>>(rstart, csre, ofx, afx);
  k_h1<<<dim3((Nn*64+255)/256), dim3(256), 0, stream>>>(afx, Wgc1, h1b);
  k_gcn2<<<dim3(Nn/4), dim3(256), 0, stream>>>(rstart, csre, h1b, Wgc2, Wgc3,
      ofx, oz, omu, olv, ogz);
  k_spmm16<<<dim3(Nn/16), dim3(256), 0, stream>>>(rstart, csre, omu, amu);
  k_dec<<<dim3(Nn/64), dim3(256), 0, stream>>>(afx, amu, WdT2, ode, srr);
  k_q<<<dim3((Nn+255)/256), dim3(256), 0, stream>>>(oz, clus, oq);
  k_lossred<<<dim3(64), dim3(256), 0, stream>>>(afx, amu, wx, sii, srr, mask, lpart);
  k_lsum<<<dim3(1), dim3(64), 0, stream>>>(lpart, olo);
}

// Round 5
// 634.149 us; speedup vs baseline: 1.2315x; 1.0087x over previous
//
#include <hip/hip_runtime.h>
#include <hip/hip_bf16.h>
#include <math.h>

#define Nn 80000
#define Dd 1000
#define Ee 1280000
#define MM 64000
#define SB 1024
#define NB 79   // ceil(Nn/SB)
#define NT 32   // K tiles of 32

typedef __attribute__((ext_vector_type(8))) short bf16x8;
typedef __attribute__((ext_vector_type(4))) float f32x4;
typedef __attribute__((ext_vector_type(4))) int i32x4;

__device__ inline unsigned short f2bf(float f){
  union { float f; unsigned u; } c; c.f = f;
  unsigned u = c.u;
  u += 0x7FFFu + ((u >> 16) & 1u);
  return (unsigned short)(u >> 16);
}
__device__ inline float bf2f(unsigned short s){
  return __uint_as_float(((unsigned)s) << 16);
}

__device__ __forceinline__ void gload16(const void* g, void* l){
  __builtin_amdgcn_global_load_lds(
      (const __attribute__((address_space(1))) void*)g,
      (__attribute__((address_space(3))) void*)l, 16, 0, 0);
}

__device__ __forceinline__ bf16x8 cvt8(f32x4 a, f32x4 b){
  union { __hip_bfloat162 h; unsigned u; } c0, c1, c2, c3;
  c0.h = __float22bfloat162_rn(make_float2(a.x, a.y));
  c1.h = __float22bfloat162_rn(make_float2(a.z, a.w));
  c2.h = __float22bfloat162_rn(make_float2(b.x, b.y));
  c3.h = __float22bfloat162_rn(make_float2(b.z, b.w));
  union { unsigned u[4]; bf16x8 v; } r;
  r.u[0] = c0.u; r.u[1] = c1.u; r.u[2] = c2.u; r.u[3] = c3.u;
  return r.v;
}

// ---- init: Wim compact swizzled B image [32][128 rows][32 bf16]; WdT2;
//      tw[97]; zero flags/deg -------------------------------------------------
__global__ __launch_bounds__(256) void k_init(const float* __restrict__ W1,
    const float* __restrict__ Wdec, const float* __restrict__ token,
    unsigned short* __restrict__ Wim, unsigned short* __restrict__ WdT2,
    float* __restrict__ tw, int* __restrict__ flags, int* __restrict__ deg)
{
  int i = blockIdx.x*256 + threadIdx.x;   // grid 665 blocks = 170240 threads
  if (i < 131072){                        // Wim: 32 tiles x 128 rows x 32 bf16
    int t   = i >> 12;
    int rem = i & 4095;
    int c   = rem >> 5;                   // row (col of W) 0..127
    int pos = rem & 31;
    int slot = pos >> 3;                  // 16B unit in LDS
    int j    = pos & 7;
    int u    = slot ^ (c & 3);            // pre-applied swizzle
    int k    = t*32 + u*8 + j;
    float v = 0.f;
    if (c < 96 && k < Dd) v = (c < 64) ? W1[k*64 + c] : Wdec[(size_t)(c-64)*Dd + k];
    Wim[i] = f2bf(v);
  }
  unsigned t1 = (unsigned)(i - 131072);
  if (t1 < 32256u){                       // WdT2[col][k] = Wdec[k][col]
    int col = t1 >> 5, k = t1 & 31;
    WdT2[t1] = (col < Dd) ? f2bf(Wdec[(size_t)k*Dd + col]) : (unsigned short)0;
  }
  if (i < Nn){ flags[i] = 0; deg[i] = 0; }
  unsigned u3 = (unsigned)(i - 163840);
  if (u3 < 6208u){                        // tw: one wave per output j
    int j = u3 >> 6, l = u3 & 63;
    float s = 0.f;
    if (j < 64){ for (int k = l; k < Dd; k += 64) s += token[k]*W1[k*64 + j]; }
    else if (j < 96){ const float* wr = Wdec + (size_t)(j-64)*Dd;
                      for (int k = l; k < Dd; k += 64) s += token[k]*wr[k]; }
    else { for (int k = l; k < Dd; k += 64) s += token[k]*token[k]; }
    #pragma unroll
    for (int o = 32; o; o >>= 1) s += __shfl_down(s, o);
    if (l == 0) tw[j] = s;
  }
}

// ---- scatter mask flags + degree histogram --------------------------------
__global__ __launch_bounds__(256) void k_scatter(const int* __restrict__ mask,
    const int* __restrict__ rows, int* __restrict__ flags, int* __restrict__ deg)
{
  int i = blockIdx.x*256 + threadIdx.x;
  if (i < MM) flags[mask[i]] = 1;
  if (i < Ee) atomicAdd(&deg[rows[i]], 1);
}

// ---- hierarchical scan -----------------------------------------------------
__global__ __launch_bounds__(256) void k_scan1(const int* __restrict__ deg,
    int* __restrict__ bsum)
{
  int base = blockIdx.x*SB + threadIdx.x*4;
  int s = 0;
  if (base + 3 < Nn){
    i32x4 v = *reinterpret_cast<const i32x4*>(&deg[base]);
    s = v.x + v.y + v.z + v.w;
  } else {
    for (int j = 0; j < 4; ++j) if (base + j < Nn) s += deg[base + j];
  }
  #pragma unroll
  for (int o = 32; o; o >>= 1) s += __shfl_down(s, o);
  __shared__ int red[4];
  if ((threadIdx.x & 63) == 0) red[threadIdx.x >> 6] = s;
  __syncthreads();
  if (threadIdx.x == 0) bsum[blockIdx.x] = red[0] + red[1] + red[2] + red[3];
}

__global__ __launch_bounds__(128) void k_scan2(int* __restrict__ bsum,
    int* __restrict__ rstart)
{
  __shared__ int sh[NB];
  int t = threadIdx.x;
  if (t < NB) sh[t] = bsum[t];
  __syncthreads();
  if (t == 0){
    int r = 0;
    for (int j = 0; j < NB; ++j){ int v = sh[j]; sh[j] = r; r += v; }
    rstart[Nn] = r;
  }
  __syncthreads();
  if (t < NB) bsum[t] = sh[t];
}

__global__ __launch_bounds__(256) void k_scan3(const int* __restrict__ deg,
    const int* __restrict__ bsum, int* __restrict__ rstart, int* __restrict__ cursor)
{
  __shared__ int tsum[256];
  __shared__ int pref[256];
  int t = threadIdx.x;
  int base = blockIdx.x*SB + t*4;
  int d0=0,d1=0,d2=0,d3=0;
  if (base + 3 < Nn){
    i32x4 v = *reinterpret_cast<const i32x4*>(&deg[base]);
    d0=v.x; d1=v.y; d2=v.z; d3=v.w;
  } else {
    if (base   < Nn) d0 = deg[base];
    if (base+1 < Nn) d1 = deg[base+1];
    if (base+2 < Nn) d2 = deg[base+2];
    if (base+3 < Nn) d3 = deg[base+3];
  }
  tsum[t] = d0+d1+d2+d3;
  __syncthreads();
  if (t == 0){
    int r = 0;
    for (int j = 0; j < 256; ++j){ pref[j] = r; r += tsum[j]; }
  }
  __syncthreads();
  int off = pref[t] + bsum[blockIdx.x];
  int o0 = off, o1 = off+d0, o2 = off+d0+d1, o3 = off+d0+d1+d2;
  if (base + 3 < Nn){
    i32x4 w; w.x=o0; w.y=o1; w.z=o2; w.w=o3;
    *reinterpret_cast<i32x4*>(&rstart[base]) = w;
    *reinterpret_cast<i32x4*>(&cursor[base]) = w;
  } else {
    if (base   < Nn){ rstart[base]=o0;   cursor[base]=o0; }
    if (base+1 < Nn){ rstart[base+1]=o1; cursor[base+1]=o1; }
    if (base+2 < Nn){ rstart[base+2]=o2; cursor[base+2]=o2; }
    if (base+3 < Nn){ rstart[base+3]=o3; cursor[base+3]=o3; }
  }
}

// ---- CSR fill (paired col+val) ----------------------------------------------
__global__ __launch_bounds__(256) void k_fill(const int* __restrict__ rows,
    const int* __restrict__ cols, const float* __restrict__ vals,
    int* __restrict__ cursor, int2* __restrict__ csre)
{
  int e = blockIdx.x*256 + threadIdx.x;
  if (e >= Ee) return;
  int r = rows[e];
  int p = atomicAdd(&cursor[r], 1);
  int2 pr; pr.x = cols[e]; pr.y = __float_as_int(vals[e]);
  csre[p] = pr;
}

// ---- GEMM1: async-pipelined [out_x]@[W1|WdecT] + BN/ELU + enc L2 + sii ------
// LDS map (bytes): A0 0..16384, A1 16384..32768, B0 32768..40960,
//                  B1 40960..49152, token 49152..53248.
// Phase2 reuse: Hs 0..33792, W2s 36864..40960.
__global__ __launch_bounds__(256, 3) void k_gemm1(
    const float* __restrict__ x, const unsigned short* __restrict__ Wim,
    const int* __restrict__ flags, const float* __restrict__ tw,
    const float* __restrict__ token,
    const float* __restrict__ b1, const float* __restrict__ g1,
    const float* __restrict__ be1, const float* __restrict__ rm1,
    const float* __restrict__ rv1, const float* __restrict__ W2,
    const float* __restrict__ b2, const float* __restrict__ g2,
    const float* __restrict__ be2, const float* __restrict__ rm2,
    const float* __restrict__ rv2, float* __restrict__ fx,
    float* __restrict__ wx, float* __restrict__ sii_node)
{
  __shared__ char smem[53248];
  float* tokL = (float*)(smem + 49152);
  const int tid  = threadIdx.x;
  const int lane = tid & 63;
  const int wave = tid >> 6;
  const int wm = wave >> 1, wn = wave & 1;
  const int l15 = lane & 15, kg = lane >> 4;
  const int swz = l15 & 7;
  const int row0 = blockIdx.x * 128;

  for (int i = tid; i < 1024; i += 256) tokL[i] = (i < Dd) ? token[i] : 0.f;
  __syncthreads();   // token visible before loop; before async stages

  auto stage = [&](int t, char* Ab, char* Bb){
    int k0 = t*32;
    #pragma unroll
    for (int j = 0; j < 4; ++j){           // A: 16KB, 4 x 1KB chunks/wave
      int s = (wave*4 + j)*64 + lane;
      int r = s >> 3, u = s & 7;
      int col = k0 + ((u ^ (r & 7)) << 2);
      if (col > 996) col = 996;
      gload16(x + (size_t)(row0 + r)*Dd + col, Ab + (wave*4 + j)*1024);
    }
    const char* wim = (const char*)Wim + (size_t)t*8192;
    #pragma unroll
    for (int j = 0; j < 2; ++j){           // B: 8KB, 2 x 1KB chunks/wave
      int ch = wave*2 + j;
      gload16(wim + ch*1024 + lane*16, Bb + ch*1024);
    }
  };

  stage(0, smem,         smem + 32768);
  stage(1, smem + 16384, smem + 40960);

  const f32x4 zero4 = {0.f,0.f,0.f,0.f};
  f32x4 acc[4][3];
  #pragma unroll
  for (int i = 0; i < 4; ++i){ acc[i][0]=zero4; acc[i][1]=zero4; acc[i][2]=zero4; }
  float sx2[4] = {0.f,0.f,0.f,0.f};
  float sxt[4] = {0.f,0.f,0.f,0.f};

  #pragma unroll 2
  for (int t = 0; t < NT; ++t){
    if (t < NT-1) asm volatile("s_waitcnt vmcnt(6)" ::: "memory");
    else          asm volatile("s_waitcnt vmcnt(0)" ::: "memory");
    __builtin_amdgcn_s_barrier();
    __builtin_amdgcn_sched_barrier(0);

    const char* Ab = smem + (t&1)*16384;
    const char* Bb = smem + 32768 + (t&1)*8192;
    const int k0 = t*32;

    f32x4 tk0 = *(const f32x4*)(tokL + k0 + kg*8);
    f32x4 tk1 = *(const f32x4*)(tokL + k0 + kg*8 + 4);

    bf16x8 bfr[3];
    #pragma unroll
    for (int ni = 0; ni < 3; ++ni){
      int c = wn*48 + ni*16 + l15;
      bfr[ni] = *(const bf16x8*)(Bb + c*64 + ((kg ^ (c & 3)) << 4));
    }
    bool kv = (k0 + kg*8) <= 992;
    #pragma unroll
    for (int mi = 0; mi < 4; ++mi){
      int r = wm*64 + mi*16 + l15;
      f32x4 xa = *(const f32x4*)(Ab + r*128 + (((2*kg  ) ^ swz) << 4));
      f32x4 xb = *(const f32x4*)(Ab + r*128 + (((2*kg+1) ^ swz) << 4));
      if (wn == 0 && kv){
        sx2[mi] += xa.x*xa.x + xa.y*xa.y + xa.z*xa.z + xa.w*xa.w
                 + xb.x*xb.x + xb.y*xb.y + xb.z*xb.z + xb.w*xb.w;
        sxt[mi] += xa.x*tk0.x + xa.y*tk0.y + xa.z*tk0.z + xa.w*tk0.w
                 + xb.x*tk1.x + xb.y*tk1.y + xb.z*tk1.z + xb.w*tk1.w;
      }
      bf16x8 af = cvt8(xa, xb);
      acc[mi][0] = __builtin_amdgcn_mfma_f32_16x16x32_bf16(af, bfr[0], acc[mi][0], 0, 0, 0);
      acc[mi][1] = __builtin_amdgcn_mfma_f32_16x16x32_bf16(af, bfr[1], acc[mi][1], 0, 0, 0);
      acc[mi][2] = __builtin_amdgcn_mfma_f32_16x16x32_bf16(af, bfr[2], acc[mi][2], 0, 0, 0);
    }

    __builtin_amdgcn_sched_barrier(0);
    __builtin_amdgcn_s_barrier();
    if (t + 2 < NT)
      stage(t+2, smem + (t&1)*16384, smem + 32768 + (t&1)*8192);
  }

  // sii: reduce across kg groups (xor 16, 32); wn==0 waves own it
  float stt = tw[96];
  if (wn == 0){
    #pragma unroll
    for (int mi = 0; mi < 4; ++mi){
      float a2 = sx2[mi]; a2 += __shfl_xor(a2, 16); a2 += __shfl_xor(a2, 32);
      float at = sxt[mi]; at += __shfl_xor(at, 16); at += __shfl_xor(at, 32);
      if (lane < 16){
        int row = row0 + wm*64 + mi*16 + lane;
        float fl = flags[row] ? 1.f : 0.f;
        sii_node[row] = a2 + fl*(2.f*at + stt);
      }
    }
  }

  // per-output-row flags
  float flv[4][4];
  #pragma unroll
  for (int mi = 0; mi < 4; ++mi)
    #pragma unroll
    for (int r4 = 0; r4 < 4; ++r4)
      flv[mi][r4] = flags[row0 + wm*64 + mi*16 + (lane>>4)*4 + r4] ? 1.f : 0.f;

  float* Hs  = (float*)smem;
  float* W2s = (float*)(smem + 36864);
  for (int i = tid; i < 1024; i += 256) W2s[i] = W2[i];

  // epilogue: cols <64 -> BN1+ELU into Hs; cols >=64 -> wx
  #pragma unroll
  for (int ni = 0; ni < 3; ++ni){
    int n = wn*48 + ni*16 + l15;
    float twn = tw[n];
    if (n < 64){
      float bb = b1[n], rmv = rm1[n];
      float scv = g1[n]*rsqrtf(rv1[n] + 1e-3f), bev = be1[n];
      #pragma unroll
      for (int mi = 0; mi < 4; ++mi){
        #pragma unroll
        for (int r4 = 0; r4 < 4; ++r4){
          int lrow = wm*64 + mi*16 + (lane>>4)*4 + r4;
          float v = (acc[mi][ni][r4] + flv[mi][r4]*twn + bb - rmv)*scv + bev;
          v = (v > 0.f) ? v : expm1f(v);
          Hs[lrow*66 + n] = v;
        }
      }
    } else {
      int j = n - 64;
      #pragma unroll
      for (int mi = 0; mi < 4; ++mi){
        #pragma unroll
        for (int r4 = 0; r4 < 4; ++r4){
          int lrow = wm*64 + mi*16 + (lane>>4)*4 + r4;
          wx[(size_t)(row0 + lrow)*32 + j] = acc[mi][ni][r4] + flv[mi][r4]*twn;
        }
      }
    }
  }
  __syncthreads();

  // phase 2: fx = elu(bn2(Hs @ W2 + b2))
  {
    int j = tid & 15;
    float pb = b2[j], prm = rm2[j];
    float psc = g2[j]*rsqrtf(rv2[j] + 1e-3f), pbe = be2[j];
    int rb = (tid >> 4) * 8;
    #pragma unroll
    for (int rr = 0; rr < 8; ++rr){
      int r = rb + rr;
      float a = pb;
      #pragma unroll
      for (int k = 0; k < 64; ++k) a += Hs[r*66 + k]*W2s[k*16 + j];
      float v = (a - prm)*psc + pbe;
      v = (v > 0.f) ? v : expm1f(v);
      fx[(size_t)(row0 + r)*16 + j] = v;
    }
  }
}

// ---- SpMM F=16 (+ optional fused h1 = relu(out_row @ Wgc1) -> bf16) ---------
template<bool WITH_H1>
__global__ __launch_bounds__(256) void k_spmm16(const int* __restrict__ rstart,
    const int2* __restrict__ csre, const float* __restrict__ in,
    float* __restrict__ out, const float* __restrict__ Wgc1,
    unsigned short* __restrict__ h1b)
{
  __shared__ float Ws[1024];
  if (WITH_H1){
    for (int t = threadIdx.x; t < 1024; t += 256) Ws[t] = Wgc1[t];
    __syncthreads();
  }
  int row = blockIdx.x*16 + (threadIdx.x >> 4);
  int l = threadIdx.x & 15;
  int s = rstart[row], e = rstart[row+1];
  float acc = 0.f;
  for (int p = s; p < e; ++p){
    int2 ce = csre[p];
    acc += __int_as_float(ce.y) * in[(size_t)ce.x*16 + l];
  }
  out[(size_t)row*16 + l] = acc;
  if (WITH_H1){
    float h0=0.f, h1=0.f, h2=0.f, h3=0.f;
    #pragma unroll
    for (int k = 0; k < 16; ++k){
      float av = __shfl(acc, k, 16);
      const float* wp = &Ws[k*64 + l*4];
      h0 += av*wp[0]; h1 += av*wp[1]; h2 += av*wp[2]; h3 += av*wp[3];
    }
    ushort4 pk;
    pk.x = f2bf(fmaxf(h0, 0.f)); pk.y = f2bf(fmaxf(h1, 0.f));
    pk.z = f2bf(fmaxf(h2, 0.f)); pk.w = f2bf(fmaxf(h3, 0.f));
    *reinterpret_cast<ushort4*>(&h1b[(size_t)row*64 + l*4]) = pk;
  }
}

// ---- GCN2: ah = A@h1 (bf16 gather), mu/lv/z/gz, fused q ---------------------
__global__ __launch_bounds__(256) void k_gcn2(const int* __restrict__ rstart,
    const int2* __restrict__ csre, const unsigned short* __restrict__ h1b,
    const float* __restrict__ Wgc2, const float* __restrict__ Wgc3,
    const float* __restrict__ fx, const float* __restrict__ cl,
    float* __restrict__ z, float* __restrict__ mu,
    float* __restrict__ lv, float* __restrict__ gz, float* __restrict__ q)
{
  __shared__ float ah[4][65];
  __shared__ float Ws[2048];
  __shared__ float cls[320];
  __shared__ float zs[4][32];
  __shared__ float qv[4][10];
  int t = threadIdx.x;
  for (int i = t; i < 1024; i += 256){ Ws[i] = Wgc2[i]; Ws[1024 + i] = Wgc3[i]; }
  for (int i = t; i < 320; i += 256) cls[i] = cl[i];
  int row = blockIdx.x*4 + (t >> 6);
  int lane = t & 63;
  int s = rstart[row], e = rstart[row+1];
  float acc = 0.f;
  for (int p = s; p < e; ++p){
    int2 ce = csre[p];
    acc += __int_as_float(ce.y) * bf2f(h1b[(size_t)ce.x*64 + lane]);
  }
  ah[t>>6][lane] = acc;
  __syncthreads();
  if (t < 128){
    int r = t >> 5, idx = t & 31, j = idx & 15, which = idx >> 4;
    const float* Wp = Ws + which*1024;
    const float* ar = ah[r];
    float sacc = 0.f;
    #pragma unroll 16
    for (int k = 0; k < 64; ++k) sacc += ar[k]*Wp[k*16 + j];
    size_t grow = (size_t)(blockIdx.x*4 + r);
    if (which == 0){
      mu[grow*16 + j] = sacc;
      gz[grow*16 + j] = sacc;
      z[grow*32 + 16 + j] = sacc;
      zs[r][16 + j] = sacc;
    } else {
      lv[grow*16 + j] = sacc;
    }
  } else {
    int u = t - 128;
    int r = u >> 5, idx = u & 31;
    if (idx < 16){
      size_t grow = (size_t)(blockIdx.x*4 + r);
      float v = fx[grow*16 + idx];
      z[grow*32 + idx] = v;
      zs[r][idx] = v;
    }
  }
  __syncthreads();
  if (t < 40){
    int r = t / 10, c = t - r*10;
    float d2 = 0.f;
    #pragma unroll
    for (int k = 0; k < 32; ++k){ float d = zs[r][k] - cls[c*32 + k]; d2 += d*d; }
    qv[r][c] = 1.f/(1.f + d2);
  }
  __syncthreads();
  if (t < 40){
    int r = t / 10, c = t - r*10;
    float ssum = 0.f;
    #pragma unroll
    for (int cc = 0; cc < 10; ++cc) ssum += qv[r][cc];
    q[(size_t)(blockIdx.x*4 + r)*10 + c] = qv[r][c]/ssum;
  }
}

// ---- decoder (transposed MFMA, f32x4 stores) + full loss term fused ---------
__global__ __launch_bounds__(256) void k_dec(const float* __restrict__ afx,
    const float* __restrict__ amu, const unsigned short* __restrict__ WdT2,
    const float* __restrict__ wx, const float* __restrict__ sii_node,
    float* __restrict__ de, float* __restrict__ term_node)
{
  const int lane = threadIdx.x & 63;
  const int wave = threadIdx.x >> 6;
  const int r0 = blockIdx.x*64 + wave*16;
  const int kg = lane >> 4;
  const int l15 = lane & 15;
  const int row = r0 + l15;
  const float* asrc = (kg < 2) ? (afx + (size_t)row*16 + kg*8)
                               : (amu + (size_t)row*16 + (kg-2)*8);
  f32x4 a0 = *reinterpret_cast<const f32x4*>(asrc);
  f32x4 a1 = *reinterpret_cast<const f32x4*>(asrc + 4);
  bf16x8 af = cvt8(a0, a1);            // B-operand: az row (col of D-tile)
  const float* wsrc = wx + (size_t)row*32 + kg*8;
  f32x4 w0 = *reinterpret_cast<const f32x4*>(wsrc);
  f32x4 w1 = *reinterpret_cast<const f32x4*>(wsrc + 4);
  float sri = a0.x*w0.x + a0.y*w0.y + a0.z*w0.z + a0.w*w0.w
            + a1.x*w1.x + a1.y*w1.y + a1.z*w1.z + a1.w*w1.w;

  const f32x4 zero4 = {0.f,0.f,0.f,0.f};
  float sq = 0.f;
  float* drow = de + (size_t)row*Dd;
  #pragma unroll 3
  for (int c0 = 0; c0 < 1008; c0 += 16){
    bf16x8 bf = *reinterpret_cast<const bf16x8*>(&WdT2[(size_t)(c0 + l15)*32 + kg*8]);
    // A-operand = Wdec^T frag (rows of D-tile = de columns)
    f32x4 d = __builtin_amdgcn_mfma_f32_16x16x32_bf16(bf, af, zero4, 0, 0, 0);
    int cb = c0 + kg*4;
    if (cb < Dd){
      *reinterpret_cast<f32x4*>(drow + cb) = d;
      sq += d[0]*d[0] + d[1]*d[1] + d[2]*d[2] + d[3]*d[3];
    }
  }
  sq  += __shfl_xor(sq, 16);  sq  += __shfl_xor(sq, 32);
  sri += __shfl_xor(sri, 16); sri += __shfl_xor(sri, 32);
  if (kg == 0){
    float nr = fmaxf(sqrtf(sq), 1e-12f);
    float ni = fmaxf(sqrtf(sii_node[row]), 1e-12f);
    float tt = 1.f - sri/(nr*ni);
    term_node[row] = tt*tt*tt;
  }
}

// ---- loss gather + reduce ----------------------------------------------------
__global__ __launch_bounds__(256) void k_lossred(const float* __restrict__ term_node,
    const int* __restrict__ mask, float* __restrict__ lpart)
{
  int i = blockIdx.x*256 + threadIdx.x;
  float s = 0.f;
  for (int w = i; w < MM; w += 64*256) s += term_node[mask[w]];
  #pragma unroll
  for (int o = 32; o; o >>= 1) s += __shfl_down(s, o);
  __shared__ float red[4];
  if ((threadIdx.x & 63) == 0) red[threadIdx.x >> 6] = s;
  __syncthreads();
  if (threadIdx.x == 0) lpart[blockIdx.x] = red[0] + red[1] + red[2] + red[3];
}

__global__ __launch_bounds__(64) void k_lsum(const float* __restrict__ lpart,
    float* __restrict__ loss)
{
  float v = lpart[threadIdx.x];
  #pragma unroll
  for (int o = 32; o; o >>= 1) v += __shfl_down(v, o);
  if (threadIdx.x == 0) *loss = v * (1.f/MM);
}

// ---- launch ------------------------------------------------------------------
extern "C" void kernel_launch(void* const* d_in, const int* in_sizes, int n_in,
                              void* d_out, int out_size, void* d_ws, size_t ws_size,
                              hipStream_t stream)
{
  const float* x     = (const float*)d_in[0];
  const int*   erow  = (const int*)  d_in[1];
  const int*   ecol  = (const int*)  d_in[2];
  const float* evls  = (const float*)d_in[3];
  const int*   mask  = (const int*)  d_in[4];
  const float* token = (const float*)d_in[5];
  const float* W1  = (const float*)d_in[6];
  const float* b1  = (const float*)d_in[7];
  const float* g1  = (const float*)d_in[8];
  const float* be1 = (const float*)d_in[9];
  const float* rm1 = (const float*)d_in[10];
  const float* rv1 = (const float*)d_in[11];
  const float* W2  = (const float*)d_in[12];
  const float* b2  = (const float*)d_in[13];
  const float* g2  = (const float*)d_in[14];
  const float* be2 = (const float*)d_in[15];
  const float* rm2 = (const float*)d_in[16];
  const float* rv2 = (const float*)d_in[17];
  const float* Wgc1= (const float*)d_in[18];
  const float* Wgc2= (const float*)d_in[19];
  const float* Wgc3= (const float*)d_in[20];
  const float* Wdec= (const float*)d_in[21];
  const float* clus= (const float*)d_in[22];

  float* out = (float*)d_out;
  float* oz  = out;
  float* omu = out + (size_t)Nn*32;
  float* olv = omu + (size_t)Nn*16;
  float* ode = olv + (size_t)Nn*16;
  float* oq  = ode + (size_t)Nn*1000;
  float* ofx = oq  + (size_t)Nn*10;
  float* ogz = ofx + (size_t)Nn*16;
  float* olo = ogz + (size_t)Nn*16;

  char* w = (char*)d_ws;
  unsigned short* Wim  = (unsigned short*)w; w += (size_t)262144;      // 32*128*32*2
  unsigned short* WdT2 = (unsigned short*)w; w += (size_t)64512;       // 1008*32*2
  float* tw    = (float*)w; w += 512;
  int* flags   = (int*)w;   w += (size_t)Nn*4;
  int* deg     = (int*)w;   w += (size_t)Nn*4;
  int* rstart  = (int*)w;   w += (size_t)320512;
  int* cursor  = (int*)w;   w += (size_t)Nn*4;
  int* bsum    = (int*)w;   w += 512;
  int2* csre   = (int2*)w;  w += (size_t)Ee*8;
  float* afx   = (float*)w; w += (size_t)Nn*16*4;
  float* amu   = (float*)w; w += (size_t)Nn*16*4;
  unsigned short* h1b = (unsigned short*)w; w += (size_t)Nn*64*2;
  float* wx    = (float*)w; w += (size_t)Nn*32*4;
  float* sii   = (float*)w; w += (size_t)Nn*4;
  float* term  = (float*)w; w += (size_t)Nn*4;
  float* lpart = (float*)w; w += 512;

  k_init<<<dim3(665), dim3(256), 0, stream>>>(W1, Wdec, token, Wim, WdT2, tw, flags, deg);
  k_scatter<<<dim3((Ee+255)/256), dim3(256), 0, stream>>>(mask, erow, flags, deg);
  k_scan1<<<dim3(NB), dim3(256), 0, stream>>>(deg, bsum);
  k_scan2<<<dim3(1), dim3(128), 0, stream>>>(bsum, rstart);
  k_scan3<<<dim3(NB), dim3(256), 0, stream>>>(deg, bsum, rstart, cursor);
  k_fill<<<dim3((Ee+255)/256), dim3(256), 0, stream>>>(erow, ecol, evls, cursor, csre);
  k_gemm1<<<dim3(Nn/128), dim3(256), 0, stream>>>(x, Wim, flags, tw, token,
      b1, g1, be1, rm1, rv1, W2, b2, g2, be2, rm2, rv2, ofx, wx, sii);
  k_spmm16<true><<<dim3(Nn/16), dim3(256), 0, stream>>>(rstart, csre, ofx, afx, Wgc1, h1b);
  k_gcn2<<<dim3(Nn/4), dim3(256), 0, stream>>>(rstart, csre, h1b, Wgc2, Wgc3,
      ofx, clus, oz, omu, olv, ogz, oq);
  k_spmm16<false><<<dim3(Nn/16), dim3(256), 0, stream>>>(rstart, csre, omu, amu, nullptr, nullptr);
  k_dec<<<dim3(Nn/64), dim3(256), 0, stream>>>(afx, amu, WdT2, wx, sii, ode, term);
  k_lossred<<<dim3(64), dim3(256), 0, stream>>>(term, mask, lpart);
  k_lsum<<<dim3(1), dim3(64), 0, stream>>>(lpart, olo);
}